// Round 4
// baseline (882.581 us; speedup 1.0000x reference)
//
#include <hip/hip_runtime.h>
#include <hip/hip_bf16.h>

// HeteroGAT: 2-relation GAT, N=100000, IN=OUT=128, E=320000/rel.
// Dtype facts (R1-R3 evidence): inputs f32 on the wire (R1 NaN =
// f32-read-as-bf16 signature; R3 detector chose f32 and matched R2 exactly),
// OUTPUT f32 (reference returns f32; harness contract "else float*"; R2/R3
// bf16 writes gave identical full-scale garbage 4.664). The test's "(bf16)"
// label is the comparison mode (bf16-emulated np ref, threshold 7.8e-2).
// d_out doubles as the f32 scatter accumulator (memset 0, atomicAdd).

typedef __bf16 bf16x8 __attribute__((ext_vector_type(8)));
typedef __bf16 bf16x2 __attribute__((ext_vector_type(2)));
typedef float f32x4 __attribute__((ext_vector_type(4)));

#define DIM 128

// ---------------- dtype detector (insurance; ~2us) ----------------
// flag = 1 if external float buffers are bf16, 0 if f32. x ~ N(0,1):
// f32-read-as-bf16 garbage has max ~1e30 over 4096 samples, real bf16 < 6.
__global__ void detect_kernel(const unsigned short* __restrict__ xu,
                              unsigned* __restrict__ flag)
{
    const int lane = threadIdx.x;  // 64 threads
    float m = 0.f;
    for (int i = lane; i < 4096; i += 64) {
        float v = __uint_as_float((unsigned)xu[i] << 16);  // decode as bf16
        v = fabsf(v);
        if (!(v < 1e29f)) v = 1e30f;                       // NaN/Inf -> huge
        m = fmaxf(m, v);
    }
#pragma unroll
    for (int off = 32; off; off >>= 1) m = fmaxf(m, __shfl_xor(m, off));
    if (lane == 0) *flag = (m < 1e4f) ? 1u : 0u;
}

// ---------------- wh = bf16(x) @ bf16(W) + b  -> bf16 wh ----------------
// Block = 256 = 4 waves; wave owns 16 rows, block 64. W converted+transposed
// into LDS bf16 (stride 136: 16B-aligned b128 reads, 2-way-free conflicts).
// A-frags straight from global (x rows have zero reuse).
__global__ __launch_bounds__(256) void gemm_wh_kernel(
    const void* __restrict__ x, const void* __restrict__ W,
    const void* __restrict__ bias, const unsigned* __restrict__ flag,
    __bf16* __restrict__ wh, int N)
{
    __shared__ __align__(16) __bf16 lWt[128 * 136];  // Wt[n][k]
    const int bf = (int)*flag;
    const int tid = threadIdx.x;
    for (int i = tid; i < 128 * 128; i += 256) {
        int k = i >> 7, n = i & 127;
        float wv = bf ? (float)((const __bf16*)W)[i] : ((const float*)W)[i];
        lWt[n * 136 + k] = (__bf16)wv;
    }
    __syncthreads();

    const int lane = tid & 63;
    const int wave = tid >> 6;
    const int quad = lane >> 4;
    const int mr   = lane & 15;

    const long row0 = (long)blockIdx.x * 64 + wave * 16;
    long arow = row0 + mr;
    if (arow >= N) arow = N - 1;                 // clamp; results discarded
    const f32x4*  xrf = (const f32x4*)((const float*)x + arow * DIM);
    const bf16x8* xrb = (const bf16x8*)((const __bf16*)x + arow * DIM);

    f32x4 zero = {0.f, 0.f, 0.f, 0.f};
    f32x4 acc[8];
#pragma unroll
    for (int t = 0; t < 8; ++t) acc[t] = zero;

    if (bf) {
#pragma unroll
        for (int ko = 0; ko < 128; ko += 32) {
            bf16x8 afrag = xrb[(ko >> 3) + quad];
#pragma unroll
            for (int ct = 0; ct < 8; ++ct) {
                bf16x8 bfrag = *(const bf16x8*)(&lWt[(ct * 16 + mr) * 136 + ko + quad * 8]);
                acc[ct] = __builtin_amdgcn_mfma_f32_16x16x32_bf16(afrag, bfrag, acc[ct], 0, 0, 0);
            }
        }
    } else {
#pragma unroll
        for (int ko = 0; ko < 128; ko += 32) {
            const int jb = (ko >> 2) + quad * 2;
            f32x4 lo = xrf[jb], hi = xrf[jb + 1];
            bf16x8 afrag = { (__bf16)lo.x, (__bf16)lo.y, (__bf16)lo.z, (__bf16)lo.w,
                             (__bf16)hi.x, (__bf16)hi.y, (__bf16)hi.z, (__bf16)hi.w };
#pragma unroll
            for (int ct = 0; ct < 8; ++ct) {
                bf16x8 bfrag = *(const bf16x8*)(&lWt[(ct * 16 + mr) * 136 + ko + quad * 8]);
                acc[ct] = __builtin_amdgcn_mfma_f32_16x16x32_bf16(afrag, bfrag, acc[ct], 0, 0, 0);
            }
        }
    }

    // C/D layout: col = lane&15, row = quad*4 + reg   [m89-verified]
#pragma unroll
    for (int ct = 0; ct < 8; ++ct) {
        const int c = ct * 16 + mr;
        const float bn = bf ? (float)((const __bf16*)bias)[c] : ((const float*)bias)[c];
#pragma unroll
        for (int r = 0; r < 4; ++r) {
            const long orow = row0 + quad * 4 + r;
            if (orow < N) wh[orow * DIM + c] = (__bf16)(acc[ct][r] + bn);
        }
    }
}

// ---------------- per-node attention scores ----------------
// s_src[i] = wh[i]·a[0:128], s_dst[i] = wh[i]·a[128:256]. One wave per row.
__global__ __launch_bounds__(256) void node_scores_kernel(
    const __bf16* __restrict__ wh, const void* __restrict__ a,
    const unsigned* __restrict__ flag,
    float* __restrict__ s_src, float* __restrict__ s_dst, int N)
{
    const int bf = (int)*flag;
    const int lane = threadIdx.x & 63;
    const int row  = blockIdx.x * 4 + (threadIdx.x >> 6);
    if (row >= N) return;
    const __bf16* ab = (const __bf16*)a;
    const float*  af = (const float*)a;
    float a0 = bf ? (float)ab[2 * lane]           : af[2 * lane];
    float a1 = bf ? (float)ab[2 * lane + 1]       : af[2 * lane + 1];
    float a2 = bf ? (float)ab[DIM + 2 * lane]     : af[DIM + 2 * lane];
    float a3 = bf ? (float)ab[DIM + 2 * lane + 1] : af[DIM + 2 * lane + 1];
    bf16x2 v = *(const bf16x2*)(wh + (long)row * DIM + lane * 2);
    float vx = (float)v.x, vy = (float)v.y;
    float ps = vx * a0 + vy * a1;
    float pd = vx * a2 + vy * a3;
#pragma unroll
    for (int off = 32; off; off >>= 1) {
        ps += __shfl_xor(ps, off);
        pd += __shfl_xor(pd, off);
    }
    if (lane == 0) { s_src[row] = ps; s_dst[row] = pd; }
}

// ---------------- edge pass 1: leaky_relu score + segment max ----------------
__device__ __forceinline__ unsigned enc_f32(float f) {
    unsigned u = __float_as_uint(f);
    return (u & 0x80000000u) ? ~u : (u | 0x80000000u);
}
__device__ __forceinline__ float dec_f32(unsigned u) {
    return (u & 0x80000000u) ? __uint_as_float(u ^ 0x80000000u) : __uint_as_float(~u);
}

__global__ __launch_bounds__(256) void edge_max_kernel(
    const int* __restrict__ src, const int* __restrict__ dst,
    const float* __restrict__ s_src, const float* __restrict__ s_dst,
    float* __restrict__ e, unsigned* __restrict__ mEnc, int E)
{
    int i = blockIdx.x * 256 + threadIdx.x;
    if (i >= E) return;
    int s = src[i], d = dst[i];
    float v = s_src[s] + s_dst[d];
    v = v > 0.f ? v : 0.01f * v;          // leaky_relu slope 0.01
    e[i] = v;
    atomicMax(mEnc + d, enc_f32(v));
}

// ---------------- edge pass 2: exp + segment sum ----------------
__global__ __launch_bounds__(256) void edge_exp_kernel(
    const int* __restrict__ dst, const float* __restrict__ e,
    const unsigned* __restrict__ mEnc, float* __restrict__ ex,
    float* __restrict__ denom, int E)
{
    int i = blockIdx.x * 256 + threadIdx.x;
    if (i >= E) return;
    int d = dst[i];
    float m = dec_f32(mEnc[d]);
    float xv = __expf(e[i] - m);          // e - m <= 0
    ex[i] = xv;
    atomicAdd(denom + d, xv);
}

// ---------------- edge pass 3: out[dst] += alpha * wh[src] (f32 atomics) ----
__global__ __launch_bounds__(256) void scatter_kernel(
    const int* __restrict__ src, const int* __restrict__ dst,
    const float* __restrict__ ex, const float* __restrict__ denom,
    const __bf16* __restrict__ wh, float* __restrict__ out, int E)
{
    const int lane = threadIdx.x & 63;
    const int nw = gridDim.x * 4;
    for (int i = blockIdx.x * 4 + (threadIdx.x >> 6); i < E; i += nw) {
        int s = src[i], d = dst[i];
        float alpha = ex[i] / denom[d];   // denom >= exp(0) = 1
        bf16x2 w = *(const bf16x2*)(wh + (long)s * DIM + lane * 2);
        float* op = out + (long)d * DIM + lane * 2;
        atomicAdd(op,     alpha * (float)w.x);
        atomicAdd(op + 1, alpha * (float)w.y);
    }
}

extern "C" void kernel_launch(void* const* d_in, const int* in_sizes, int n_in,
                              void* d_out, int out_size, void* d_ws, size_t ws_size,
                              hipStream_t stream) {
    const void* x = d_in[0];
    const int* srcs[2] = {(const int*)d_in[1], (const int*)d_in[3]};
    const int* dsts[2] = {(const int*)d_in[2], (const int*)d_in[4]};
    const void* Ws[2] = {d_in[5], d_in[8]};
    const void* Bs[2] = {d_in[6], d_in[9]};
    const void* As[2] = {d_in[7], d_in[10]};

    const int N = in_sizes[0] / DIM;
    const int E = in_sizes[1];
    float* out = (float*)d_out;   // f32 output == scatter accumulator

    // workspace carve-up (~30 MB); mEnc+denom adjacent for one memset
    char* p = (char*)d_ws;
    unsigned* flag  = (unsigned*)p; p += 256;
    __bf16*   wh    = (__bf16*)p;   p += (size_t)N * DIM * 2;
    unsigned* mEnc  = (unsigned*)p; p += (size_t)N * 4;
    float*    denom = (float*)p;    p += (size_t)N * 4;
    float*    s_src = (float*)p;    p += (size_t)N * 4;
    float*    s_dst = (float*)p;    p += (size_t)N * 4;
    float*    e     = (float*)p;    p += (size_t)E * 4;
    float*    ex    = (float*)p;    p += (size_t)E * 4;

    detect_kernel<<<1, 64, 0, stream>>>((const unsigned short*)x, flag);
    hipMemsetAsync(out, 0, (size_t)N * DIM * 4, stream);

    for (int r = 0; r < 2; ++r) {
        hipMemsetAsync(mEnc, 0, (size_t)N * 8, stream);  // mEnc + denom
        gemm_wh_kernel<<<(N + 63) / 64, 256, 0, stream>>>(x, Ws[r], Bs[r], flag, wh, N);
        node_scores_kernel<<<(N + 3) / 4, 256, 0, stream>>>(wh, As[r], flag, s_src, s_dst, N);
        edge_max_kernel<<<(E + 255) / 256, 256, 0, stream>>>(srcs[r], dsts[r], s_src, s_dst, e, mEnc, E);
        edge_exp_kernel<<<(E + 255) / 256, 256, 0, stream>>>(dsts[r], e, mEnc, ex, denom, E);
        scatter_kernel<<<4096, 256, 0, stream>>>(srcs[r], dsts[r], ex, denom, wh, out, E);
    }
}

// Round 5
// 305.377 us; speedup vs baseline: 2.8901x; 2.8901x over previous
//
#include <hip/hip_runtime.h>
#include <hip/hip_bf16.h>

// HeteroGAT: 2-relation GAT, N=100000, IN=OUT=128, E=320000/rel.
// Dtypes (R1-R4 verified): inputs f32, output f32 (d_out is the f32 result).
// R4 passed at 882us with atomic scatter = 60% of time (atomic-bound: 18% HBM,
// 5.7% VALU). R5: CSR-by-dst counting sort + one fused per-dst online-softmax
// gather kernel -> zero f32 atomics, out written once. Scores fused into GEMM
// epilogue.

typedef __bf16 bf16x8 __attribute__((ext_vector_type(8)));
typedef __bf16 bf16x2 __attribute__((ext_vector_type(2)));
typedef float f32x4 __attribute__((ext_vector_type(4)));

#define DIM 128

// ---- wh = bf16(x) @ bf16(W) + b -> bf16 wh; fused s_src/s_dst epilogue ----
// Block = 256 = 4 waves; wave owns 16 rows, block 64. W converted+transposed
// into LDS bf16, row stride 136 elems (272B = 68 dwords === 4 mod 32 banks:
// mr and mr+8 alias -> free 2-way; 16B-aligned b128 reads).
__global__ __launch_bounds__(256) void gemm_wh_kernel(
    const float* __restrict__ x, const float* __restrict__ W,
    const float* __restrict__ bias, const float* __restrict__ a,
    __bf16* __restrict__ wh, float* __restrict__ s_src,
    float* __restrict__ s_dst, int N)
{
    __shared__ __align__(16) __bf16 lWt[128 * 136];  // Wt[n][k]
    const int tid = threadIdx.x;
    for (int i = tid; i < 128 * 128; i += 256) {
        int k = i >> 7, n = i & 127;
        lWt[n * 136 + k] = (__bf16)W[i];
    }
    __syncthreads();

    const int lane = tid & 63;
    const int wave = tid >> 6;
    const int quad = lane >> 4;
    const int mr   = lane & 15;

    const long row0 = (long)blockIdx.x * 64 + wave * 16;
    long arow = row0 + mr;
    if (arow >= N) arow = N - 1;               // clamp; results discarded
    const f32x4* xr = (const f32x4*)(x + arow * DIM);

    f32x4 zero = {0.f, 0.f, 0.f, 0.f};
    f32x4 acc[8];
#pragma unroll
    for (int t = 0; t < 8; ++t) acc[t] = zero;

#pragma unroll
    for (int ko = 0; ko < 128; ko += 32) {
        const int jb = (ko >> 2) + quad * 2;
        f32x4 lo = xr[jb], hi = xr[jb + 1];
        bf16x8 afrag = { (__bf16)lo.x, (__bf16)lo.y, (__bf16)lo.z, (__bf16)lo.w,
                         (__bf16)hi.x, (__bf16)hi.y, (__bf16)hi.z, (__bf16)hi.w };
#pragma unroll
        for (int ct = 0; ct < 8; ++ct) {
            bf16x8 bfrag = *(const bf16x8*)(&lWt[(ct * 16 + mr) * 136 + ko + quad * 8]);
            acc[ct] = __builtin_amdgcn_mfma_f32_16x16x32_bf16(afrag, bfrag, acc[ct], 0, 0, 0);
        }
    }

    // Epilogue. C/D layout: col = ct*16 + mr, row = quad*4 + r [m89-verified].
    // Also accumulate per-row score partials: ps = a[0:128].wh, pd = a[128:].wh
    float psr[4] = {0.f, 0.f, 0.f, 0.f};
    float pdr[4] = {0.f, 0.f, 0.f, 0.f};
#pragma unroll
    for (int ct = 0; ct < 8; ++ct) {
        const int c = ct * 16 + mr;
        const float bn = bias[c];
        const float asc = a[c], adc = a[DIM + c];
#pragma unroll
        for (int r = 0; r < 4; ++r) {
            const float wv = acc[ct][r] + bn;
            const long orow = row0 + quad * 4 + r;
            if (orow < N) wh[orow * DIM + c] = (__bf16)wv;
            psr[r] += asc * wv;
            pdr[r] += adc * wv;
        }
    }
    // reduce over mr (16 lanes within quad); offsets <16 stay inside the quad
#pragma unroll
    for (int off = 1; off < 16; off <<= 1) {
#pragma unroll
        for (int r = 0; r < 4; ++r) {
            psr[r] += __shfl_xor(psr[r], off);
            pdr[r] += __shfl_xor(pdr[r], off);
        }
    }
    if (mr == 0) {
#pragma unroll
        for (int r = 0; r < 4; ++r) {
            const long orow = row0 + quad * 4 + r;
            if (orow < N) { s_src[orow] = psr[r]; s_dst[orow] = pdr[r]; }
        }
    }
}

// ---------------- CSR build: count ----------------
__global__ __launch_bounds__(256) void count_kernel(
    const int* __restrict__ dst0, const int* __restrict__ dst1,
    unsigned* __restrict__ deg, int N, int E)
{
    int i = blockIdx.x * 256 + threadIdx.x;
    if (i >= E) return;
    atomicAdd(deg + dst0[i], 1u);
    atomicAdd(deg + N + dst1[i], 1u);
}

// ---------------- CSR build: 3-kernel exclusive scan over deg[0..n) ----------
__global__ __launch_bounds__(256) void scanA_kernel(
    const unsigned* __restrict__ deg, unsigned* __restrict__ tmp,
    unsigned* __restrict__ bsum, int n)
{
    __shared__ unsigned s[256];
    const int t = threadIdx.x;
    const int i = blockIdx.x * 256 + t;
    unsigned v = (i < n) ? deg[i] : 0u;
    s[t] = v;
    __syncthreads();
#pragma unroll
    for (int off = 1; off < 256; off <<= 1) {
        unsigned add = (t >= off) ? s[t - off] : 0u;
        __syncthreads();
        s[t] += add;
        __syncthreads();
    }
    if (i < n) tmp[i] = s[t] - v;            // exclusive within block
    if (t == 255) bsum[blockIdx.x] = s[t];   // block total
}

// single block; assumes nb <= 1024 (nb = 782 here)
__global__ __launch_bounds__(256) void scanB_kernel(
    const unsigned* __restrict__ bsum, unsigned* __restrict__ bsumEx, int nb)
{
    __shared__ unsigned s[256];
    const int t = threadIdx.x;
    unsigned loc[4], sum = 0u;
#pragma unroll
    for (int k = 0; k < 4; ++k) {
        int idx = t * 4 + k;
        loc[k] = (idx < nb) ? bsum[idx] : 0u;
        sum += loc[k];
    }
    s[t] = sum;
    __syncthreads();
#pragma unroll
    for (int off = 1; off < 256; off <<= 1) {
        unsigned add = (t >= off) ? s[t - off] : 0u;
        __syncthreads();
        s[t] += add;
        __syncthreads();
    }
    unsigned run = s[t] - sum;               // exclusive over chunks
#pragma unroll
    for (int k = 0; k < 4; ++k) {
        int idx = t * 4 + k;
        if (idx < nb) bsumEx[idx] = run;
        run += loc[k];
    }
}

__global__ __launch_bounds__(256) void scanC_kernel(
    const unsigned* __restrict__ tmp, const unsigned* __restrict__ bsumEx,
    const unsigned* __restrict__ deg, unsigned* __restrict__ rowptr,
    unsigned* __restrict__ cursor, int n)
{
    const int i = blockIdx.x * 256 + threadIdx.x;
    if (i >= n) return;
    unsigned val = tmp[i] + bsumEx[blockIdx.x];
    rowptr[i] = val;
    cursor[i] = val;
    if (i == n - 1) rowptr[n] = val + deg[i];
}

// ---------------- CSR build: fill sorted src ids ----------------
__global__ __launch_bounds__(256) void fill_kernel(
    const int* __restrict__ src0, const int* __restrict__ dst0,
    const int* __restrict__ src1, const int* __restrict__ dst1,
    unsigned* __restrict__ cursor, unsigned* __restrict__ sorted_src,
    int N, int E)
{
    int i = blockIdx.x * 256 + threadIdx.x;
    if (i >= E) return;
    unsigned p0 = atomicAdd(cursor + dst0[i], 1u);
    sorted_src[p0] = (unsigned)src0[i];
    unsigned p1 = atomicAdd(cursor + N + dst1[i], 1u);
    sorted_src[p1] = (unsigned)src1[i];
}

// ---------------- fused per-dst online-softmax aggregate ----------------
// One wave per dst node; lane covers 2 of 128 cols. Both relations in one
// pass; out written exactly once (no memset, no atomics).
__global__ __launch_bounds__(256) void aggregate_kernel(
    const unsigned* __restrict__ rowptr, const unsigned* __restrict__ sorted_src,
    const float* __restrict__ s_src, const float* __restrict__ s_dst,
    const __bf16* __restrict__ wh, float* __restrict__ out, int N)
{
    const int lane = threadIdx.x & 63;
    const int d = blockIdx.x * 4 + (threadIdx.x >> 6);
    if (d >= N) return;

    float2 accT = {0.f, 0.f};
#pragma unroll
    for (int r = 0; r < 2; ++r) {
        const int base = r * N + d;
        const unsigned beg = rowptr[base], end = rowptr[base + 1];
        if (beg == end) continue;            // isolated dst: contributes 0
        const float sd = s_dst[base];
        const float* ss = s_src + (size_t)r * N;
        const __bf16* whr = wh + (size_t)r * N * DIM;

        float m = -1e30f, l = 0.f;
        float2 acc = {0.f, 0.f};
        for (unsigned j = beg; j < end; ++j) {
            const unsigned s = sorted_src[j];
            float v = ss[s] + sd;
            v = v > 0.f ? v : 0.01f * v;     // leaky_relu slope 0.01
            bf16x2 w = *(const bf16x2*)(whr + (size_t)s * DIM + lane * 2);
            if (v > m) {                     // wave-uniform branch
                const float sc = __expf(m - v);
                l *= sc; acc.x *= sc; acc.y *= sc; m = v;
            }
            const float p = __expf(v - m);
            l += p;
            acc.x += p * (float)w.x;
            acc.y += p * (float)w.y;
        }
        const float inv = 1.f / l;           // l >= exp(0) = 1
        accT.x += acc.x * inv;
        accT.y += acc.y * inv;
    }
    *(float2*)(out + (size_t)d * DIM + lane * 2) = accT;
}

extern "C" void kernel_launch(void* const* d_in, const int* in_sizes, int n_in,
                              void* d_out, int out_size, void* d_ws, size_t ws_size,
                              hipStream_t stream) {
    const float* x = (const float*)d_in[0];
    const int* srcs[2] = {(const int*)d_in[1], (const int*)d_in[3]};
    const int* dsts[2] = {(const int*)d_in[2], (const int*)d_in[4]};
    const float* Ws[2] = {(const float*)d_in[5], (const float*)d_in[8]};
    const float* Bs[2] = {(const float*)d_in[6], (const float*)d_in[9]};
    const float* As[2] = {(const float*)d_in[7], (const float*)d_in[10]};

    const int N = in_sizes[0] / DIM;
    const int E = in_sizes[1];
    const int n2 = 2 * N;                       // combined deg/scan length
    const int nb = (n2 + 255) / 256;            // scan blocks (782)
    float* out = (float*)d_out;                 // f32 result, written once

    // workspace carve-up (~58 MB)
    char* p = (char*)d_ws;
    __bf16*   wh     = (__bf16*)p;   p += (size_t)n2 * DIM * 2;  // wh0|wh1
    float*    s_src  = (float*)p;    p += (size_t)n2 * 4;
    float*    s_dst  = (float*)p;    p += (size_t)n2 * 4;
    unsigned* deg    = (unsigned*)p; p += (size_t)n2 * 4;
    unsigned* tmp    = (unsigned*)p; p += (size_t)n2 * 4;
    unsigned* rowptr = (unsigned*)p; p += (size_t)(n2 + 1) * 4;
    unsigned* cursor = (unsigned*)p; p += (size_t)n2 * 4;
    unsigned* ssrc   = (unsigned*)p; p += (size_t)2 * E * 4;     // sorted srcs
    unsigned* bsum   = (unsigned*)p; p += (size_t)nb * 4;
    unsigned* bsumEx = (unsigned*)p; p += (size_t)nb * 4;

    hipMemsetAsync(deg, 0, (size_t)n2 * 4, stream);

    for (int r = 0; r < 2; ++r)
        gemm_wh_kernel<<<(N + 63) / 64, 256, 0, stream>>>(
            x, Ws[r], Bs[r], As[r], wh + (size_t)r * N * DIM,
            s_src + (size_t)r * N, s_dst + (size_t)r * N, N);

    count_kernel<<<(E + 255) / 256, 256, 0, stream>>>(dsts[0], dsts[1], deg, N, E);
    scanA_kernel<<<nb, 256, 0, stream>>>(deg, tmp, bsum, n2);
    scanB_kernel<<<1, 256, 0, stream>>>(bsum, bsumEx, nb);
    scanC_kernel<<<nb, 256, 0, stream>>>(tmp, bsumEx, deg, rowptr, cursor, n2);
    fill_kernel<<<(E + 255) / 256, 256, 0, stream>>>(
        srcs[0], dsts[0], srcs[1], dsts[1], cursor, ssrc, N, E);
    aggregate_kernel<<<(N + 3) / 4, 256, 0, stream>>>(
        rowptr, ssrc, s_src, s_dst, wh, out, N);
}

// Round 6
// 292.950 us; speedup vs baseline: 3.0127x; 1.0424x over previous
//
#include <hip/hip_runtime.h>
#include <hip/hip_bf16.h>

// HeteroGAT: 2-relation GAT, N=100000, IN=OUT=128, E=320000/rel.
// Dtypes (R1-R4 verified): inputs f32, output f32.
// R5: 305us. aggregate=86us latency-bound (22% HBM, 39% VALU): serial
// online-softmax chain, 1 wave per dst. R6: (a) no-max softmax (|e|<~5,
// exp safe in f32; alpha identical) -> independent edge iterations,
// unroll-by-2; (b) one wave per (dst,relation), LDS combine (2x waves);
// (c) GEMM: both relations in one launch, 128 rows/block (halves W-stage).

typedef __bf16 bf16x8 __attribute__((ext_vector_type(8)));
typedef __bf16 bf16x2 __attribute__((ext_vector_type(2)));
typedef float f32x4 __attribute__((ext_vector_type(4)));

#define DIM 128

// ---- wh = bf16(x) @ bf16(W) + b -> bf16 wh; fused s_src/s_dst epilogue ----
// Grid (ceil(N/128), 2): blockIdx.y = relation. Block = 256 = 4 waves; wave
// owns 32 rows (2 MFMA row-tiles), block 128 rows. W converted+transposed
// into LDS bf16, stride 136 (16B-aligned b128 reads).
__global__ __launch_bounds__(256) void gemm_wh_kernel(
    const float* __restrict__ x,
    const float* __restrict__ W0, const float* __restrict__ W1,
    const float* __restrict__ b0, const float* __restrict__ b1,
    const float* __restrict__ a0, const float* __restrict__ a1,
    __bf16* __restrict__ wh, float* __restrict__ s_src,
    float* __restrict__ s_dst, int N)
{
    const int rel = blockIdx.y;
    const float* W    = rel ? W1 : W0;
    const float* bias = rel ? b1 : b0;
    const float* a    = rel ? a1 : a0;
    __bf16* whr  = wh    + (size_t)rel * N * DIM;
    float*  ssr  = s_src + (size_t)rel * N;
    float*  sdr  = s_dst + (size_t)rel * N;

    __shared__ __align__(16) __bf16 lWt[128 * 136];  // Wt[n][k]
    const int tid = threadIdx.x;
    for (int i = tid; i < 128 * 128; i += 256) {
        int k = i >> 7, n = i & 127;
        lWt[n * 136 + k] = (__bf16)W[i];
    }
    __syncthreads();

    const int lane = tid & 63;
    const int wave = tid >> 6;
    const int quad = lane >> 4;
    const int mr   = lane & 15;

    const long wrow0 = (long)blockIdx.x * 128 + wave * 32;

    f32x4 zero = {0.f, 0.f, 0.f, 0.f};
    f32x4 acc[2][8];
#pragma unroll
    for (int rt = 0; rt < 2; ++rt)
#pragma unroll
        for (int t = 0; t < 8; ++t) acc[rt][t] = zero;

#pragma unroll
    for (int rt = 0; rt < 2; ++rt) {
        long arow = wrow0 + rt * 16 + mr;
        if (arow >= N) arow = N - 1;           // clamp; results discarded
        const f32x4* xr = (const f32x4*)(x + arow * DIM);
#pragma unroll
        for (int ko = 0; ko < 128; ko += 32) {
            const int jb = (ko >> 2) + quad * 2;
            f32x4 lo = xr[jb], hi = xr[jb + 1];
            bf16x8 afrag = { (__bf16)lo.x, (__bf16)lo.y, (__bf16)lo.z, (__bf16)lo.w,
                             (__bf16)hi.x, (__bf16)hi.y, (__bf16)hi.z, (__bf16)hi.w };
#pragma unroll
            for (int ct = 0; ct < 8; ++ct) {
                bf16x8 bfrag = *(const bf16x8*)(&lWt[(ct * 16 + mr) * 136 + ko + quad * 8]);
                acc[rt][ct] = __builtin_amdgcn_mfma_f32_16x16x32_bf16(afrag, bfrag, acc[rt][ct], 0, 0, 0);
            }
        }
    }

    // Epilogue. C/D: col = ct*16+mr, row = quad*4+r [m89-verified]. Fused
    // score partials ps = a[0:128]·wh_row, pd = a[128:]·wh_row.
#pragma unroll
    for (int rt = 0; rt < 2; ++rt) {
        const long row0 = wrow0 + rt * 16;
        float psr[4] = {0.f, 0.f, 0.f, 0.f};
        float pdr[4] = {0.f, 0.f, 0.f, 0.f};
#pragma unroll
        for (int ct = 0; ct < 8; ++ct) {
            const int c = ct * 16 + mr;
            const float bn = bias[c];
            const float asc = a[c], adc = a[DIM + c];
#pragma unroll
            for (int r = 0; r < 4; ++r) {
                const float wv = acc[rt][ct][r] + bn;
                const long orow = row0 + quad * 4 + r;
                if (orow < N) whr[orow * DIM + c] = (__bf16)wv;
                psr[r] += asc * wv;
                pdr[r] += adc * wv;
            }
        }
#pragma unroll
        for (int off = 1; off < 16; off <<= 1) {
#pragma unroll
            for (int r = 0; r < 4; ++r) {
                psr[r] += __shfl_xor(psr[r], off);
                pdr[r] += __shfl_xor(pdr[r], off);
            }
        }
        if (mr == 0) {
#pragma unroll
            for (int r = 0; r < 4; ++r) {
                const long orow = row0 + quad * 4 + r;
                if (orow < N) { ssr[orow] = psr[r]; sdr[orow] = pdr[r]; }
            }
        }
    }
}

// ---------------- CSR build: count ----------------
__global__ __launch_bounds__(256) void count_kernel(
    const int* __restrict__ dst0, const int* __restrict__ dst1,
    unsigned* __restrict__ deg, int N, int E)
{
    int i = blockIdx.x * 256 + threadIdx.x;
    if (i >= E) return;
    atomicAdd(deg + dst0[i], 1u);
    atomicAdd(deg + N + dst1[i], 1u);
}

// ---------------- CSR build: 3-kernel exclusive scan ----------------
__global__ __launch_bounds__(256) void scanA_kernel(
    const unsigned* __restrict__ deg, unsigned* __restrict__ tmp,
    unsigned* __restrict__ bsum, int n)
{
    __shared__ unsigned s[256];
    const int t = threadIdx.x;
    const int i = blockIdx.x * 256 + t;
    unsigned v = (i < n) ? deg[i] : 0u;
    s[t] = v;
    __syncthreads();
#pragma unroll
    for (int off = 1; off < 256; off <<= 1) {
        unsigned add = (t >= off) ? s[t - off] : 0u;
        __syncthreads();
        s[t] += add;
        __syncthreads();
    }
    if (i < n) tmp[i] = s[t] - v;
    if (t == 255) bsum[blockIdx.x] = s[t];
}

// single block; nb <= 1024 (782 here)
__global__ __launch_bounds__(256) void scanB_kernel(
    const unsigned* __restrict__ bsum, unsigned* __restrict__ bsumEx, int nb)
{
    __shared__ unsigned s[256];
    const int t = threadIdx.x;
    unsigned loc[4], sum = 0u;
#pragma unroll
    for (int k = 0; k < 4; ++k) {
        int idx = t * 4 + k;
        loc[k] = (idx < nb) ? bsum[idx] : 0u;
        sum += loc[k];
    }
    s[t] = sum;
    __syncthreads();
#pragma unroll
    for (int off = 1; off < 256; off <<= 1) {
        unsigned add = (t >= off) ? s[t - off] : 0u;
        __syncthreads();
        s[t] += add;
        __syncthreads();
    }
    unsigned run = s[t] - sum;
#pragma unroll
    for (int k = 0; k < 4; ++k) {
        int idx = t * 4 + k;
        if (idx < nb) bsumEx[idx] = run;
        run += loc[k];
    }
}

__global__ __launch_bounds__(256) void scanC_kernel(
    const unsigned* __restrict__ tmp, const unsigned* __restrict__ bsumEx,
    const unsigned* __restrict__ deg, unsigned* __restrict__ rowptr,
    unsigned* __restrict__ cursor, int n)
{
    const int i = blockIdx.x * 256 + threadIdx.x;
    if (i >= n) return;
    unsigned val = tmp[i] + bsumEx[blockIdx.x];
    rowptr[i] = val;
    cursor[i] = val;
    if (i == n - 1) rowptr[n] = val + deg[i];
}

// ---------------- CSR build: fill sorted src ids ----------------
__global__ __launch_bounds__(256) void fill_kernel(
    const int* __restrict__ src0, const int* __restrict__ dst0,
    const int* __restrict__ src1, const int* __restrict__ dst1,
    unsigned* __restrict__ cursor, unsigned* __restrict__ sorted_src,
    int N, int E)
{
    int i = blockIdx.x * 256 + threadIdx.x;
    if (i >= E) return;
    unsigned p0 = atomicAdd(cursor + dst0[i], 1u);
    sorted_src[p0] = (unsigned)src0[i];
    unsigned p1 = atomicAdd(cursor + N + dst1[i], 1u);
    sorted_src[p1] = (unsigned)src1[i];
}

// ---------------- fused per-(dst,relation) softmax-aggregate ----------------
// One wave per (dst, relation); lane covers 2 of 128 cols. No max-subtraction
// (|e| <~ 5; exp safe in f32; alpha mathematically identical) -> independent
// edge iterations, unrolled by 2 for MLP. Rel-1 wave passes its result via
// LDS; rel-0 wave adds and writes out exactly once.
__global__ __launch_bounds__(256) void aggregate_kernel(
    const unsigned* __restrict__ rowptr, const unsigned* __restrict__ sorted_src,
    const float* __restrict__ s_src, const float* __restrict__ s_dst,
    const __bf16* __restrict__ wh, float* __restrict__ out, int N)
{
    __shared__ float lacc[2][128];
    const int tid  = threadIdx.x;
    const int lane = tid & 63;
    const int wave = tid >> 6;
    const int dloc = wave >> 1;
    const int r    = wave & 1;
    const int d    = blockIdx.x * 2 + dloc;
    const bool valid = d < N;

    float ax = 0.f, ay = 0.f, l = 0.f;
    if (valid) {
        const int base = r * N + d;
        const unsigned beg = rowptr[base], end = rowptr[base + 1];
        const float sd = s_dst[base];
        const float* ss = s_src + (size_t)r * N;
        const __bf16* whr = wh + (size_t)r * N * DIM;

        unsigned j = beg;
        for (; j + 1 < end; j += 2) {
            const unsigned s0 = sorted_src[j], s1 = sorted_src[j + 1];
            float v0 = ss[s0] + sd, v1 = ss[s1] + sd;
            v0 = v0 > 0.f ? v0 : 0.01f * v0;
            v1 = v1 > 0.f ? v1 : 0.01f * v1;
            bf16x2 w0 = *(const bf16x2*)(whr + (size_t)s0 * DIM + lane * 2);
            bf16x2 w1 = *(const bf16x2*)(whr + (size_t)s1 * DIM + lane * 2);
            const float e0 = __expf(v0), e1 = __expf(v1);
            l  += e0 + e1;
            ax += e0 * (float)w0.x + e1 * (float)w1.x;
            ay += e0 * (float)w0.y + e1 * (float)w1.y;
        }
        if (j < end) {
            const unsigned s0 = sorted_src[j];
            float v0 = ss[s0] + sd;
            v0 = v0 > 0.f ? v0 : 0.01f * v0;
            bf16x2 w0 = *(const bf16x2*)(whr + (size_t)s0 * DIM + lane * 2);
            const float e0 = __expf(v0);
            l  += e0;
            ax += e0 * (float)w0.x;
            ay += e0 * (float)w0.y;
        }
        const float inv = (l > 0.f) ? 1.f / l : 0.f;  // l==0: isolated dst
        ax *= inv; ay *= inv;
    }

    if (r == 1 && valid) {
        lacc[dloc][lane * 2]     = ax;
        lacc[dloc][lane * 2 + 1] = ay;
    }
    __syncthreads();
    if (r == 0 && valid) {
        float2 o;
        o.x = ax + lacc[dloc][lane * 2];
        o.y = ay + lacc[dloc][lane * 2 + 1];
        *(float2*)(out + (size_t)d * DIM + lane * 2) = o;
    }
}

extern "C" void kernel_launch(void* const* d_in, const int* in_sizes, int n_in,
                              void* d_out, int out_size, void* d_ws, size_t ws_size,
                              hipStream_t stream) {
    const float* x = (const float*)d_in[0];
    const int* srcs[2] = {(const int*)d_in[1], (const int*)d_in[3]};
    const int* dsts[2] = {(const int*)d_in[2], (const int*)d_in[4]};
    const float* Ws[2] = {(const float*)d_in[5], (const float*)d_in[8]};
    const float* Bs[2] = {(const float*)d_in[6], (const float*)d_in[9]};
    const float* As[2] = {(const float*)d_in[7], (const float*)d_in[10]};

    const int N = in_sizes[0] / DIM;
    const int E = in_sizes[1];
    const int n2 = 2 * N;
    const int nb = (n2 + 255) / 256;            // scan blocks (782)
    float* out = (float*)d_out;

    // workspace carve-up (~58 MB)
    char* p = (char*)d_ws;
    __bf16*   wh     = (__bf16*)p;   p += (size_t)n2 * DIM * 2;  // wh0|wh1
    float*    s_src  = (float*)p;    p += (size_t)n2 * 4;
    float*    s_dst  = (float*)p;    p += (size_t)n2 * 4;
    unsigned* deg    = (unsigned*)p; p += (size_t)n2 * 4;
    unsigned* tmp    = (unsigned*)p; p += (size_t)n2 * 4;
    unsigned* rowptr = (unsigned*)p; p += (size_t)(n2 + 1) * 4;
    unsigned* cursor = (unsigned*)p; p += (size_t)n2 * 4;
    unsigned* ssrc   = (unsigned*)p; p += (size_t)2 * E * 4;     // sorted srcs
    unsigned* bsum   = (unsigned*)p; p += (size_t)nb * 4;
    unsigned* bsumEx = (unsigned*)p; p += (size_t)nb * 4;

    hipMemsetAsync(deg, 0, (size_t)n2 * 4, stream);

    dim3 ggrid((N + 127) / 128, 2);
    gemm_wh_kernel<<<ggrid, 256, 0, stream>>>(
        x, Ws[0], Ws[1], Bs[0], Bs[1], As[0], As[1], wh, s_src, s_dst, N);

    count_kernel<<<(E + 255) / 256, 256, 0, stream>>>(dsts[0], dsts[1], deg, N, E);
    scanA_kernel<<<nb, 256, 0, stream>>>(deg, tmp, bsum, n2);
    scanB_kernel<<<1, 256, 0, stream>>>(bsum, bsumEx, nb);
    scanC_kernel<<<nb, 256, 0, stream>>>(tmp, bsumEx, deg, rowptr, cursor, n2);
    fill_kernel<<<(E + 255) / 256, 256, 0, stream>>>(
        srcs[0], dsts[0], srcs[1], dsts[1], cursor, ssrc, N, E);
    aggregate_kernel<<<(N + 1) / 2, 256, 0, stream>>>(
        rowptr, ssrc, s_src, s_dst, wh, out, N);
}

// Round 7
// 273.865 us; speedup vs baseline: 3.2227x; 1.0697x over previous
//
#include <hip/hip_runtime.h>
#include <hip/hip_bf16.h>

// HeteroGAT: 2-relation GAT, N=100000, IN=OUT=128, E=320000/rel.
// Dtypes (R1-R4 verified): inputs f32, output f32.
// R6: 293us; aggregate 74.7us (latency-bound, 26% HBM, 47% VALU); all other
// dispatches <74.6us, ~218us smeared over gemm+CSR+gaps. R7: (a) aggregate
// processes 4 edges/iter (4x16-lane subgroups, bf16x8=16B/lane row loads,
// 4 rows in flight per instruction); (b) gemm reads x once for both rels
// (both W tiles in LDS) + LDS-staged coalesced bf16x8 wh stores; (c) edge
// count fused into gemm. 7 dispatches.

typedef __bf16 bf16x8 __attribute__((ext_vector_type(8)));
typedef float f32x4 __attribute__((ext_vector_type(4)));

#define DIM 128

// ---- wh_r = bf16(x) @ bf16(W_r) + b_r (both rels), fused scores + count ----
// Block 256 = 4 waves; wave owns 16 rows; block 64 rows. LDS: 2 transposed
// W tiles (bf16, stride 136). After the K-loop the rel-0 W region is dead and
// is reused as the C staging buffer (64x136 bf16) for coalesced stores.
__global__ __launch_bounds__(256) void gemm_wh_kernel(
    const float* __restrict__ x,
    const float* __restrict__ W0, const float* __restrict__ W1,
    const float* __restrict__ b0, const float* __restrict__ b1,
    const float* __restrict__ a0, const float* __restrict__ a1,
    const int* __restrict__ dst0, const int* __restrict__ dst1,
    unsigned* __restrict__ deg,
    __bf16* __restrict__ wh, float* __restrict__ s_src,
    float* __restrict__ s_dst, int N, int E)
{
    __shared__ __align__(16) __bf16 lW[2 * 128 * 136];  // 69632 B
    const int tid = threadIdx.x;

    // fused per-edge degree count (independent work, fire-and-forget atomics)
    {
        const int gid = blockIdx.x * 256 + tid;
        if (gid < E) {
            atomicAdd(deg + dst0[gid], 1u);
            atomicAdd(deg + N + dst1[gid], 1u);
        }
    }

    // stage both W tiles, converted + transposed: lW[r][n*136+k]
    for (int i = tid; i < 2 * 128 * 128; i += 256) {
        const int r = i >> 14, idx = i & 16383;
        const int k = idx >> 7, n = idx & 127;
        const float* W = r ? W1 : W0;
        lW[r * 17408 + n * 136 + k] = (__bf16)W[idx];
    }
    __syncthreads();

    const int lane = tid & 63;
    const int wave = tid >> 6;
    const int quad = lane >> 4;
    const int mr   = lane & 15;

    const long row0 = (long)blockIdx.x * 64 + wave * 16;
    long arow = row0 + mr;
    if (arow >= N) arow = N - 1;               // clamp; results discarded
    const f32x4* xr = (const f32x4*)(x + arow * DIM);

    f32x4 zero = {0.f, 0.f, 0.f, 0.f};
    f32x4 acc[2][8];
#pragma unroll
    for (int r = 0; r < 2; ++r)
#pragma unroll
        for (int t = 0; t < 8; ++t) acc[r][t] = zero;

#pragma unroll
    for (int ko = 0; ko < 128; ko += 32) {
        const int jb = (ko >> 2) + quad * 2;
        f32x4 lo = xr[jb], hi = xr[jb + 1];
        bf16x8 afrag = { (__bf16)lo.x, (__bf16)lo.y, (__bf16)lo.z, (__bf16)lo.w,
                         (__bf16)hi.x, (__bf16)hi.y, (__bf16)hi.z, (__bf16)hi.w };
#pragma unroll
        for (int r = 0; r < 2; ++r)
#pragma unroll
            for (int ct = 0; ct < 8; ++ct) {
                bf16x8 bfrag = *(const bf16x8*)(&lW[r * 17408 + (ct * 16 + mr) * 136 + ko + quad * 8]);
                acc[r][ct] = __builtin_amdgcn_mfma_f32_16x16x32_bf16(afrag, bfrag, acc[r][ct], 0, 0, 0);
            }
    }
    __syncthreads();                            // all K-loops done; lW[0] dead

    __bf16* Cst = lW;                           // 64x136 bf16 staging overlay
#pragma unroll
    for (int r = 0; r < 2; ++r) {
        const float* bias = r ? b1 : b0;
        const float* a    = r ? a1 : a0;
        // C/D layout: col = ct*16+mr, row = quad*4+rr [m89-verified]
        float psr[4] = {0.f, 0.f, 0.f, 0.f};
        float pdr[4] = {0.f, 0.f, 0.f, 0.f};
#pragma unroll
        for (int ct = 0; ct < 8; ++ct) {
            const int c = ct * 16 + mr;
            const float bn = bias[c];
            const float asc = a[c], adc = a[DIM + c];
#pragma unroll
            for (int rr = 0; rr < 4; ++rr) {
                const float wv = acc[r][ct][rr] + bn;
                Cst[(wave * 16 + quad * 4 + rr) * 136 + c] = (__bf16)wv;
                psr[rr] += asc * wv;
                pdr[rr] += adc * wv;
            }
        }
#pragma unroll
        for (int off = 1; off < 16; off <<= 1) {
#pragma unroll
            for (int rr = 0; rr < 4; ++rr) {
                psr[rr] += __shfl_xor(psr[rr], off);
                pdr[rr] += __shfl_xor(pdr[rr], off);
            }
        }
        if (mr == 0) {
#pragma unroll
            for (int rr = 0; rr < 4; ++rr) {
                const long orow = row0 + quad * 4 + rr;
                if (orow < N) {
                    s_src[(size_t)r * N + orow] = psr[rr];
                    s_dst[(size_t)r * N + orow] = pdr[rr];
                }
            }
        }
        __syncthreads();                        // staging complete
        // coalesced read-back: 1024 chunks of 16B; wave covers 4 full rows
#pragma unroll
        for (int i = 0; i < 4; ++i) {
            const int chunk = tid + 256 * i;
            const int row = chunk >> 4, c8 = chunk & 15;
            bf16x8 v = *(const bf16x8*)&Cst[row * 136 + c8 * 8];
            const long grow = (long)blockIdx.x * 64 + row;
            if (grow < N)
                *(bf16x8*)(wh + ((size_t)r * N + grow) * DIM + c8 * 8) = v;
        }
        __syncthreads();                        // before rel1 re-stages
    }
}

// ---------------- CSR build: 3-kernel exclusive scan ----------------
__global__ __launch_bounds__(256) void scanA_kernel(
    const unsigned* __restrict__ deg, unsigned* __restrict__ tmp,
    unsigned* __restrict__ bsum, int n)
{
    __shared__ unsigned s[256];
    const int t = threadIdx.x;
    const int i = blockIdx.x * 256 + t;
    unsigned v = (i < n) ? deg[i] : 0u;
    s[t] = v;
    __syncthreads();
#pragma unroll
    for (int off = 1; off < 256; off <<= 1) {
        unsigned add = (t >= off) ? s[t - off] : 0u;
        __syncthreads();
        s[t] += add;
        __syncthreads();
    }
    if (i < n) tmp[i] = s[t] - v;
    if (t == 255) bsum[blockIdx.x] = s[t];
}

// single block; nb <= 1024 (782 here)
__global__ __launch_bounds__(256) void scanB_kernel(
    const unsigned* __restrict__ bsum, unsigned* __restrict__ bsumEx, int nb)
{
    __shared__ unsigned s[256];
    const int t = threadIdx.x;
    unsigned loc[4], sum = 0u;
#pragma unroll
    for (int k = 0; k < 4; ++k) {
        int idx = t * 4 + k;
        loc[k] = (idx < nb) ? bsum[idx] : 0u;
        sum += loc[k];
    }
    s[t] = sum;
    __syncthreads();
#pragma unroll
    for (int off = 1; off < 256; off <<= 1) {
        unsigned add = (t >= off) ? s[t - off] : 0u;
        __syncthreads();
        s[t] += add;
        __syncthreads();
    }
    unsigned run = s[t] - sum;
#pragma unroll
    for (int k = 0; k < 4; ++k) {
        int idx = t * 4 + k;
        if (idx < nb) bsumEx[idx] = run;
        run += loc[k];
    }
}

__global__ __launch_bounds__(256) void scanC_kernel(
    const unsigned* __restrict__ tmp, const unsigned* __restrict__ bsumEx,
    const unsigned* __restrict__ deg, unsigned* __restrict__ rowptr,
    unsigned* __restrict__ cursor, int n)
{
    const int i = blockIdx.x * 256 + threadIdx.x;
    if (i >= n) return;
    unsigned val = tmp[i] + bsumEx[blockIdx.x];
    rowptr[i] = val;
    cursor[i] = val;
    if (i == n - 1) rowptr[n] = val + deg[i];
}

// ---------------- CSR build: fill sorted src ids ----------------
__global__ __launch_bounds__(256) void fill_kernel(
    const int* __restrict__ src0, const int* __restrict__ dst0,
    const int* __restrict__ src1, const int* __restrict__ dst1,
    unsigned* __restrict__ cursor, unsigned* __restrict__ sorted_src,
    int N, int E)
{
    int i = blockIdx.x * 256 + threadIdx.x;
    if (i >= E) return;
    unsigned p0 = atomicAdd(cursor + dst0[i], 1u);
    sorted_src[p0] = (unsigned)src0[i];
    unsigned p1 = atomicAdd(cursor + N + dst1[i], 1u);
    sorted_src[p1] = (unsigned)src1[i];
}

// ---------------- fused per-dst softmax-aggregate, 4 edges/iter ----------------
// One wave per dst (both rels serial). 4 subgroups x 16 lanes: each subgroup
// owns one edge, lane loads 16B (8 cols) of the src wh row -> 4 rows in
// flight per load instruction. No max-subtraction (|e|<~5, f32-safe; alpha
// identical). Cross-subgroup combine via 2 shuffles. Out written once.
__global__ __launch_bounds__(256) void aggregate_kernel(
    const unsigned* __restrict__ rowptr, const unsigned* __restrict__ sorted_src,
    const float* __restrict__ s_src, const float* __restrict__ s_dst,
    const __bf16* __restrict__ wh, float* __restrict__ out, int N)
{
    const int tid  = threadIdx.x;
    const int lane = tid & 63;
    const int sub  = lane >> 4;
    const int mr   = lane & 15;
    const int d    = blockIdx.x * 4 + (tid >> 6);
    if (d >= N) return;

    float o[8];
#pragma unroll
    for (int k = 0; k < 8; ++k) o[k] = 0.f;

#pragma unroll
    for (int r = 0; r < 2; ++r) {
        const int base = r * N + d;
        const unsigned beg = rowptr[base], end = rowptr[base + 1];
        if (beg == end) continue;               // isolated dst in this rel
        const float sd = s_dst[base];
        const float* ss = s_src + (size_t)r * N;
        const __bf16* whr = wh + (size_t)r * N * DIM;

        float l = 0.f, a[8];
#pragma unroll
        for (int k = 0; k < 8; ++k) a[k] = 0.f;

        for (unsigned j0 = beg; j0 < end; j0 += 4) {
            const unsigned j = j0 + sub;
            const bool ok = j < end;
            const unsigned s = ok ? sorted_src[j] : 0u;
            float v = ss[s] + sd;
            v = v > 0.f ? v : 0.01f * v;        // leaky_relu slope 0.01
            const float e = ok ? __expf(v) : 0.f;
            bf16x8 w = *(const bf16x8*)(whr + (size_t)s * DIM + mr * 8);
            l += e;
#pragma unroll
            for (int k = 0; k < 8; ++k) a[k] += e * (float)w[k];
        }
        // combine the 4 subgroups (lanes within a subgroup hold equal l)
        l += __shfl_xor(l, 16); l += __shfl_xor(l, 32);
#pragma unroll
        for (int k = 0; k < 8; ++k) {
            a[k] += __shfl_xor(a[k], 16);
            a[k] += __shfl_xor(a[k], 32);
        }
        const float inv = 1.f / l;              // l > 0 (exp > 0)
#pragma unroll
        for (int k = 0; k < 8; ++k) o[k] += a[k] * inv;
    }

    if (sub == 0) {                             // 16 lanes cover the 512B row
        float4 v0 = {o[0], o[1], o[2], o[3]};
        float4 v1 = {o[4], o[5], o[6], o[7]};
        float* op = out + (size_t)d * DIM + mr * 8;
        *(float4*)op       = v0;
        *(float4*)(op + 4) = v1;
    }
}

extern "C" void kernel_launch(void* const* d_in, const int* in_sizes, int n_in,
                              void* d_out, int out_size, void* d_ws, size_t ws_size,
                              hipStream_t stream) {
    const float* x = (const float*)d_in[0];
    const int* srcs[2] = {(const int*)d_in[1], (const int*)d_in[3]};
    const int* dsts[2] = {(const int*)d_in[2], (const int*)d_in[4]};
    const float* Ws[2] = {(const float*)d_in[5], (const float*)d_in[8]};
    const float* Bs[2] = {(const float*)d_in[6], (const float*)d_in[9]};
    const float* As[2] = {(const float*)d_in[7], (const float*)d_in[10]};

    const int N = in_sizes[0] / DIM;
    const int E = in_sizes[1];
    const int n2 = 2 * N;
    const int nb = (n2 + 255) / 256;            // scan blocks (782)
    float* out = (float*)d_out;

    // workspace carve-up (~58 MB)
    char* p = (char*)d_ws;
    __bf16*   wh     = (__bf16*)p;   p += (size_t)n2 * DIM * 2;  // wh0|wh1
    float*    s_src  = (float*)p;    p += (size_t)n2 * 4;
    float*    s_dst  = (float*)p;    p += (size_t)n2 * 4;
    unsigned* deg    = (unsigned*)p; p += (size_t)n2 * 4;
    unsigned* tmp    = (unsigned*)p; p += (size_t)n2 * 4;
    unsigned* rowptr = (unsigned*)p; p += (size_t)(n2 + 1) * 4;
    unsigned* cursor = (unsigned*)p; p += (size_t)n2 * 4;
    unsigned* ssrc   = (unsigned*)p; p += (size_t)2 * E * 4;     // sorted srcs
    unsigned* bsum   = (unsigned*)p; p += (size_t)nb * 4;
    unsigned* bsumEx = (unsigned*)p; p += (size_t)nb * 4;

    hipMemsetAsync(deg, 0, (size_t)n2 * 4, stream);

    // gemm grid must cover both row tiles (1563) and edge count (1250)
    const int gblocks = (N + 63) / 64;
    gemm_wh_kernel<<<gblocks, 256, 0, stream>>>(
        x, Ws[0], Ws[1], Bs[0], Bs[1], As[0], As[1],
        dsts[0], dsts[1], deg, wh, s_src, s_dst, N, E);

    scanA_kernel<<<nb, 256, 0, stream>>>(deg, tmp, bsum, n2);
    scanB_kernel<<<1, 256, 0, stream>>>(bsum, bsumEx, nb);
    scanC_kernel<<<nb, 256, 0, stream>>>(tmp, bsumEx, deg, rowptr, cursor, n2);
    fill_kernel<<<(E + 255) / 256, 256, 0, stream>>>(
        srcs[0], dsts[0], srcs[1], dsts[1], cursor, ssrc, N, E);
    aggregate_kernel<<<(N + 3) / 4, 256, 0, stream>>>(
        rowptr, ssrc, s_src, s_dst, wh, out, N);
}

// Round 8
// 262.010 us; speedup vs baseline: 3.3685x; 1.0452x over previous
//
#include <hip/hip_runtime.h>
#include <hip/hip_bf16.h>

// HeteroGAT: 2-relation GAT, N=100000, IN=OUT=128, E=320000/rel.
// Dtypes (R1-R4 verified): inputs f32, output f32.
// R7: 274us; gemm now top (77-81us): 6.6M LDS bank conflicts (8-way W-stage
// transpose writes) + 18% occupancy (69.6KB LDS = 2 blocks/CU). R8: kill the
// LDS W entirely -- prep kernel pre-bakes W^T in MFMA B-frag order (bf16,
// 64KB, L1-resident, wave-uniform coalesced loads); gemm LDS = C-staging only
// (17.4KB); per-rel acc reuse (~90 VGPR); scanB+scanC merged. 7 dispatches.

typedef __bf16 bf16x8 __attribute__((ext_vector_type(8)));
typedef float f32x4 __attribute__((ext_vector_type(4)));

#define DIM 128

// ---- prep: W^T (both rels) -> bf16 in exact B-fragment order ----
// entry e = ((rel*8 + ct)*4 + ko4)*64 + lane holds 8 bf16:
//   B[k = ko4*32 + (lane>>4)*8 + j][n = ct*16 + (lane&15)], j=0..7
__global__ __launch_bounds__(256) void prep_w_kernel(
    const float* __restrict__ W0, const float* __restrict__ W1,
    __bf16* __restrict__ wtf)
{
    const int e = blockIdx.x * 256 + threadIdx.x;   // 4096 entries
    if (e >= 4096) return;
    const int lane = e & 63;
    const int ko4  = (e >> 6) & 3;
    const int ct   = (e >> 8) & 7;
    const int rel  = e >> 11;
    const float* W = rel ? W1 : W0;
    const int n  = ct * 16 + (lane & 15);
    const int k0 = ko4 * 32 + (lane >> 4) * 8;
    bf16x8 v;
#pragma unroll
    for (int j = 0; j < 8; ++j) v[j] = (__bf16)W[(k0 + j) * DIM + n];
    *(bf16x8*)(wtf + (size_t)e * 8) = v;
}

// ---- wh_r = bf16(x) @ W_r + b_r (both rels), fused scores + edge count ----
// Block 256 = 4 waves; wave owns 16 rows; block 64 rows. No LDS for W:
// bfrags are wave-uniform coalesced 1KB global loads from wtf (L1-hit).
// A-slice (128 k) lives in 16 VGPRs bf16 across both relations.
__global__ __launch_bounds__(256) void gemm_wh_kernel(
    const float* __restrict__ x, const __bf16* __restrict__ wtf,
    const float* __restrict__ b0, const float* __restrict__ b1,
    const float* __restrict__ a0, const float* __restrict__ a1,
    const int* __restrict__ dst0, const int* __restrict__ dst1,
    unsigned* __restrict__ deg,
    __bf16* __restrict__ wh, float* __restrict__ s_src,
    float* __restrict__ s_dst, int N, int E)
{
    __shared__ __align__(16) __bf16 Cst[64 * 136];  // 17408 B C-staging
    const int tid = threadIdx.x;

    // fused per-edge degree count (independent, fire-and-forget atomics)
    {
        const int gid = blockIdx.x * 256 + tid;
        if (gid < E) {
            atomicAdd(deg + dst0[gid], 1u);
            atomicAdd(deg + N + dst1[gid], 1u);
        }
    }

    const int lane = tid & 63;
    const int wave = tid >> 6;
    const int quad = lane >> 4;
    const int mr   = lane & 15;

    const long row0 = (long)blockIdx.x * 64 + wave * 16;
    long arow = row0 + mr;
    if (arow >= N) arow = N - 1;               // clamp; results discarded
    const f32x4* xr = (const f32x4*)(x + arow * DIM);

    // full A slice for this lane: k = ko4*32 + quad*8 .. +7
    bf16x8 afrag[4];
#pragma unroll
    for (int ko4 = 0; ko4 < 4; ++ko4) {
        f32x4 lo = xr[ko4 * 8 + quad * 2], hi = xr[ko4 * 8 + quad * 2 + 1];
        afrag[ko4] = (bf16x8){ (__bf16)lo.x, (__bf16)lo.y, (__bf16)lo.z, (__bf16)lo.w,
                               (__bf16)hi.x, (__bf16)hi.y, (__bf16)hi.z, (__bf16)hi.w };
    }

    const bf16x8* wt = (const bf16x8*)wtf;

#pragma unroll
    for (int rel = 0; rel < 2; ++rel) {
        f32x4 zero = {0.f, 0.f, 0.f, 0.f};
        f32x4 acc[8];
#pragma unroll
        for (int t = 0; t < 8; ++t) acc[t] = zero;

#pragma unroll
        for (int ko4 = 0; ko4 < 4; ++ko4) {
#pragma unroll
            for (int ct = 0; ct < 8; ++ct) {
                bf16x8 bfrag = wt[((rel * 8 + ct) * 4 + ko4) * 64 + lane];
                acc[ct] = __builtin_amdgcn_mfma_f32_16x16x32_bf16(afrag[ko4], bfrag, acc[ct], 0, 0, 0);
            }
        }

        const float* bias = rel ? b1 : b0;
        const float* a    = rel ? a1 : a0;
        // C/D layout: col = ct*16+mr, row = quad*4+rr [m89-verified]
        float psr[4] = {0.f, 0.f, 0.f, 0.f};
        float pdr[4] = {0.f, 0.f, 0.f, 0.f};
#pragma unroll
        for (int ct = 0; ct < 8; ++ct) {
            const int c = ct * 16 + mr;
            const float bn = bias[c];
            const float asc = a[c], adc = a[DIM + c];
#pragma unroll
            for (int rr = 0; rr < 4; ++rr) {
                const float wv = acc[ct][rr] + bn;
                Cst[(wave * 16 + quad * 4 + rr) * 136 + c] = (__bf16)wv;
                psr[rr] += asc * wv;
                pdr[rr] += adc * wv;
            }
        }
#pragma unroll
        for (int off = 1; off < 16; off <<= 1) {
#pragma unroll
            for (int rr = 0; rr < 4; ++rr) {
                psr[rr] += __shfl_xor(psr[rr], off);
                pdr[rr] += __shfl_xor(pdr[rr], off);
            }
        }
        if (mr == 0) {
#pragma unroll
            for (int rr = 0; rr < 4; ++rr) {
                const long orow = row0 + quad * 4 + rr;
                if (orow < N) {
                    s_src[(size_t)rel * N + orow] = psr[rr];
                    s_dst[(size_t)rel * N + orow] = pdr[rr];
                }
            }
        }
        __syncthreads();                        // staging complete
        // coalesced read-back: 1024 chunks of 16B
#pragma unroll
        for (int i = 0; i < 4; ++i) {
            const int chunk = tid + 256 * i;
            const int row = chunk >> 4, c8 = chunk & 15;
            bf16x8 v = *(const bf16x8*)&Cst[row * 136 + c8 * 8];
            const long grow = (long)blockIdx.x * 64 + row;
            if (grow < N)
                *(bf16x8*)(wh + ((size_t)rel * N + grow) * DIM + c8 * 8) = v;
        }
        __syncthreads();                        // before rel1 re-stages Cst
    }
}

// ---------------- CSR scan pass 1: per-block inclusive scan ----------------
__global__ __launch_bounds__(256) void scanA_kernel(
    const unsigned* __restrict__ deg, unsigned* __restrict__ tmp,
    unsigned* __restrict__ bsum, int n)
{
    __shared__ unsigned s[256];
    const int t = threadIdx.x;
    const int i = blockIdx.x * 256 + t;
    unsigned v = (i < n) ? deg[i] : 0u;
    s[t] = v;
    __syncthreads();
#pragma unroll
    for (int off = 1; off < 256; off <<= 1) {
        unsigned add = (t >= off) ? s[t - off] : 0u;
        __syncthreads();
        s[t] += add;
        __syncthreads();
    }
    if (i < n) tmp[i] = s[t] - v;            // exclusive within block
    if (t == 255) bsum[blockIdx.x] = s[t];   // block total
}

// ---- CSR scan pass 2: each block re-scans bsum locally, writes rowptr ----
// nb <= 1024 (782 here)
__global__ __launch_bounds__(256) void scan2_kernel(
    const unsigned* __restrict__ tmp, const unsigned* __restrict__ bsum,
    const unsigned* __restrict__ deg, unsigned* __restrict__ rowptr,
    unsigned* __restrict__ cursor, int n, int nb)
{
    __shared__ unsigned s[256];
    __shared__ unsigned ex[1024];
    const int t = threadIdx.x;
    unsigned loc[4], sum = 0u;
#pragma unroll
    for (int k = 0; k < 4; ++k) {
        int idx = t * 4 + k;
        loc[k] = (idx < nb) ? bsum[idx] : 0u;
        sum += loc[k];
    }
    s[t] = sum;
    __syncthreads();
#pragma unroll
    for (int off = 1; off < 256; off <<= 1) {
        unsigned add = (t >= off) ? s[t - off] : 0u;
        __syncthreads();
        s[t] += add;
        __syncthreads();
    }
    unsigned run = s[t] - sum;
#pragma unroll
    for (int k = 0; k < 4; ++k) {
        ex[t * 4 + k] = run;
        run += loc[k];
    }
    __syncthreads();
    const unsigned pref = ex[blockIdx.x];
    const int i = blockIdx.x * 256 + t;
    if (i < n) {
        unsigned val = tmp[i] + pref;
        rowptr[i] = val;
        cursor[i] = val;
        if (i == n - 1) rowptr[n] = val + deg[i];
    }
}

// ---------------- CSR build: fill sorted src ids ----------------
__global__ __launch_bounds__(256) void fill_kernel(
    const int* __restrict__ src0, const int* __restrict__ dst0,
    const int* __restrict__ src1, const int* __restrict__ dst1,
    unsigned* __restrict__ cursor, unsigned* __restrict__ sorted_src,
    int N, int E)
{
    int i = blockIdx.x * 256 + threadIdx.x;
    if (i >= E) return;
    unsigned p0 = atomicAdd(cursor + dst0[i], 1u);
    sorted_src[p0] = (unsigned)src0[i];
    unsigned p1 = atomicAdd(cursor + N + dst1[i], 1u);
    sorted_src[p1] = (unsigned)src1[i];
}

// ---------------- fused per-dst softmax-aggregate, 4 edges/iter ----------------
// One wave per dst (both rels serial). 4 subgroups x 16 lanes: each subgroup
// owns one edge, lane loads 16B (8 cols) of the src wh row -> 4 rows in
// flight per load instruction. No max-subtraction (|e|<~5, f32-safe; alpha
// identical). Cross-subgroup combine via 2 shuffles. Out written once.
__global__ __launch_bounds__(256) void aggregate_kernel(
    const unsigned* __restrict__ rowptr, const unsigned* __restrict__ sorted_src,
    const float* __restrict__ s_src, const float* __restrict__ s_dst,
    const __bf16* __restrict__ wh, float* __restrict__ out, int N)
{
    const int tid  = threadIdx.x;
    const int lane = tid & 63;
    const int sub  = lane >> 4;
    const int mr   = lane & 15;
    const int d    = blockIdx.x * 4 + (tid >> 6);
    if (d >= N) return;

    float o[8];
#pragma unroll
    for (int k = 0; k < 8; ++k) o[k] = 0.f;

#pragma unroll
    for (int r = 0; r < 2; ++r) {
        const int base = r * N + d;
        const unsigned beg = rowptr[base], end = rowptr[base + 1];
        if (beg == end) continue;               // isolated dst in this rel
        const float sd = s_dst[base];
        const float* ss = s_src + (size_t)r * N;
        const __bf16* whr = wh + (size_t)r * N * DIM;

        float l = 0.f, a[8];
#pragma unroll
        for (int k = 0; k < 8; ++k) a[k] = 0.f;

        for (unsigned j0 = beg; j0 < end; j0 += 4) {
            const unsigned j = j0 + sub;
            const bool ok = j < end;
            const unsigned s = ok ? sorted_src[j] : 0u;
            float v = ss[s] + sd;
            v = v > 0.f ? v : 0.01f * v;        // leaky_relu slope 0.01
            const float e = ok ? __expf(v) : 0.f;
            bf16x8 w = *(const bf16x8*)(whr + (size_t)s * DIM + mr * 8);
            l += e;
#pragma unroll
            for (int k = 0; k < 8; ++k) a[k] += e * (float)w[k];
        }
        l += __shfl_xor(l, 16); l += __shfl_xor(l, 32);
#pragma unroll
        for (int k = 0; k < 8; ++k) {
            a[k] += __shfl_xor(a[k], 16);
            a[k] += __shfl_xor(a[k], 32);
        }
        const float inv = 1.f / l;              // l > 0 (exp > 0)
#pragma unroll
        for (int k = 0; k < 8; ++k) o[k] += a[k] * inv;
    }

    if (sub == 0) {                             // 16 lanes cover the 512B row
        float4 v0 = {o[0], o[1], o[2], o[3]};
        float4 v1 = {o[4], o[5], o[6], o[7]};
        float* op = out + (size_t)d * DIM + mr * 8;
        *(float4*)op       = v0;
        *(float4*)(op + 4) = v1;
    }
}

extern "C" void kernel_launch(void* const* d_in, const int* in_sizes, int n_in,
                              void* d_out, int out_size, void* d_ws, size_t ws_size,
                              hipStream_t stream) {
    const float* x = (const float*)d_in[0];
    const int* srcs[2] = {(const int*)d_in[1], (const int*)d_in[3]};
    const int* dsts[2] = {(const int*)d_in[2], (const int*)d_in[4]};
    const float* Ws[2] = {(const float*)d_in[5], (const float*)d_in[8]};
    const float* Bs[2] = {(const float*)d_in[6], (const float*)d_in[9]};
    const float* As[2] = {(const float*)d_in[7], (const float*)d_in[10]};

    const int N = in_sizes[0] / DIM;
    const int E = in_sizes[1];
    const int n2 = 2 * N;
    const int nb = (n2 + 255) / 256;            // scan blocks (782)
    float* out = (float*)d_out;

    // workspace carve-up (~58 MB)
    char* p = (char*)d_ws;
    __bf16*   wh     = (__bf16*)p;   p += (size_t)n2 * DIM * 2;  // wh0|wh1
    __bf16*   wtf    = (__bf16*)p;   p += (size_t)4096 * 8 * 2;  // 64KB frag-W
    float*    s_src  = (float*)p;    p += (size_t)n2 * 4;
    float*    s_dst  = (float*)p;    p += (size_t)n2 * 4;
    unsigned* deg    = (unsigned*)p; p += (size_t)n2 * 4;
    unsigned* tmp    = (unsigned*)p; p += (size_t)n2 * 4;
    unsigned* rowptr = (unsigned*)p; p += (size_t)(n2 + 1) * 4;
    unsigned* cursor = (unsigned*)p; p += (size_t)n2 * 4;
    unsigned* ssrc   = (unsigned*)p; p += (size_t)2 * E * 4;     // sorted srcs
    unsigned* bsum   = (unsigned*)p; p += (size_t)nb * 4;

    hipMemsetAsync(deg, 0, (size_t)n2 * 4, stream);
    prep_w_kernel<<<16, 256, 0, stream>>>(Ws[0], Ws[1], wtf);

    // gemm grid covers both row tiles (1563) and edge count (1250)
    gemm_wh_kernel<<<(N + 63) / 64, 256, 0, stream>>>(
        x, wtf, Bs[0], Bs[1], As[0], As[1],
        dsts[0], dsts[1], deg, wh, s_src, s_dst, N, E);

    scanA_kernel<<<nb, 256, 0, stream>>>(deg, tmp, bsum, n2);
    scan2_kernel<<<nb, 256, 0, stream>>>(tmp, bsum, deg, rowptr, cursor, n2, nb);
    fill_kernel<<<(E + 255) / 256, 256, 0, stream>>>(
        srcs[0], dsts[0], srcs[1], dsts[1], cursor, ssrc, N, E);
    aggregate_kernel<<<(N + 3) / 4, 256, 0, stream>>>(
        rowptr, ssrc, s_src, s_dst, wh, out, N);
}